// Round 8
// baseline (116.527 us; speedup 1.0000x reference)
//
#include <hip/hip_runtime.h>
#include <hip/hip_bf16.h>

// HGNN forward, MI355X.
// R20 = R18 (best: 112.7us) + depth-3 gather pipeline ONLY (no interleave).
// R19 bundled depth-3 + dsd/usu interleave -> 115.8 (+3.1). Attribution
// analysis: interleave was likely the culprit with REVERSED mechanism —
// dsd blocks are short (288 scattered loads) vs usu (1024); R18's tail of
// 256 dsd blocks is the OPTIMAL order, interleave pushed long usu blocks
// into the tail. Depth-3 unmeasured -> this round isolates it.
// History:
//  - R14 (k_dot fold, agent atomics): FAILED +43us (L2 thrash).
//  - R15 (32-load hoist + (512,4)): +3us — occupancy loss beat MLP.
//  - R16 (depth-2 pipeline, (512,6)): 114.2us.
//  - R17 (gather hoisted to own kernel): +7.5us — lost overlap.
//  - R18 ((512,8) = 4 blocks/CU, LDS-exact): 112.7us BEST.
//  - R19 (depth-3 + interleave bundle): 115.8 — interleave tail inversion.
// Structure:
//  - k_cvt: E_s -> bf16 table (6.4MB; halves gather lines, R5).
//  - k_main: 1024 usu blocks then 256 dsd blocks (dsd-last = short tail).
//  - k_dot: final 64-dot.

typedef __attribute__((ext_vector_type(8))) short short8;
typedef __attribute__((ext_vector_type(8))) unsigned short ushort8;
typedef __attribute__((ext_vector_type(4))) float f32x4;

__device__ __forceinline__ int rfl(int v) { return __builtin_amdgcn_readfirstlane(v); }
__device__ __forceinline__ float bcastf(float v, int l) {
    return __int_as_float(__builtin_amdgcn_readlane(__float_as_int(v), l));
}
__device__ __forceinline__ float leakyf(float x) { return x >= 0.f ? x : 0.2f * x; }

__device__ __forceinline__ unsigned short bf16bits(float x) {
    __hip_bfloat16 h = __float2bfloat16(x);
    return __builtin_bit_cast(unsigned short, h);
}
__device__ __forceinline__ float bflo(unsigned int u) { return __uint_as_float(u << 16); }
__device__ __forceinline__ float bfhi(unsigned int u) { return __uint_as_float(u & 0xffff0000u); }

// Swizzled LDS fp32 weight layout (R3-verified): element [j][k] at float4
// index 16*j + (((k>>2)+j)&15). 512-thread stager: 2 float4 per thread.
__device__ __forceinline__ void stage_w512(float* dst, const float* __restrict__ W, int tid) {
#pragma unroll
    for (int c = 0; c < 2; ++c) {
        int f4 = c * 512 + tid;
        int j = f4 >> 4, g = f4 & 15;
        float4 v = reinterpret_cast<const float4*>(W)[f4];
        reinterpret_cast<float4*>(dst)[(j << 4) + ((g + j) & 15)] = v;
    }
}

__device__ __forceinline__ float dot1_lds(float x, const float* w, int lane) {
    float a0 = 0.f, a1 = 0.f, a2 = 0.f, a3 = 0.f;
#pragma unroll
    for (int g = 0; g < 16; ++g) {
        float4 c = reinterpret_cast<const float4*>(w)[(lane << 4) + ((g + lane) & 15)];
        int k = 4 * g;
        a0 = fmaf(bcastf(x, k + 0), c.x, a0);
        a1 = fmaf(bcastf(x, k + 1), c.y, a1);
        a2 = fmaf(bcastf(x, k + 2), c.z, a2);
        a3 = fmaf(bcastf(x, k + 3), c.w, a3);
    }
    return (a0 + a1) + (a2 + a3);
}

// ---- E_s fp32 -> bf16 table ----
__global__ __launch_bounds__(256) void k_cvt(const float* __restrict__ E_s,
                                             unsigned short* __restrict__ T) {
    int t = blockIdx.x * 256 + threadIdx.x;
    if (t >= 400008) return;
    const float4* p = reinterpret_cast<const float4*>(E_s) + (size_t)t * 2;
    float4 a = p[0], b = p[1];
    ushort8 o;
    o[0] = bf16bits(a.x); o[1] = bf16bits(a.y); o[2] = bf16bits(a.z); o[3] = bf16bits(a.w);
    o[4] = bf16bits(b.x); o[5] = bf16bits(b.y); o[6] = bf16bits(b.z); o[7] = bf16bits(b.w);
    *(reinterpret_cast<ushort8*>(T) + t) = o;
}

#define XP 72   // bf16 matrix row pitch in shorts (144 B: 16B-aligned)

// 4-MFMA pair-matmul accumulate: acc += As@Wb1(K32x2) + Am@Wb2(K32x2)
__device__ __forceinline__ f32x4 pair_mfma(
    const unsigned short* sXs, const unsigned short* sXm,
    const unsigned short* sWb1, const unsigned short* sWb2,
    int arow, int brow, int quad)
{
    const int ab = arow * XP + quad * 8;
    const int bb = brow * XP + quad * 8;
    short8 as0 = *(const short8*)(sXs + ab);
    short8 as1 = *(const short8*)(sXs + ab + 32);
    short8 am0 = *(const short8*)(sXm + ab);
    short8 am1 = *(const short8*)(sXm + ab + 32);
    short8 b10 = *(const short8*)(sWb1 + bb);
    short8 b11 = *(const short8*)(sWb1 + bb + 32);
    short8 b20 = *(const short8*)(sWb2 + bb);
    short8 b21 = *(const short8*)(sWb2 + bb + 32);
    f32x4 acc = {0.f, 0.f, 0.f, 0.f};
    acc = __builtin_amdgcn_mfma_f32_16x16x32_bf16(as0, b10, acc, 0, 0, 0);
    acc = __builtin_amdgcn_mfma_f32_16x16x32_bf16(as1, b11, acc, 0, 0, 0);
    acc = __builtin_amdgcn_mfma_f32_16x16x32_bf16(am0, b20, acc, 0, 0, 0);
    acc = __builtin_amdgcn_mfma_f32_16x16x32_bf16(am1, b21, acc, 0, 0, 0);
    return acc;
}

// LDS (usu): sXb[64x72] sW3b[64x72] sW21b[64x72] sW22b[64x72] (ushort)
//            sA2[512] sES1[512] (float) = 40960 B.  4 blocks/CU = 163840 B
//            = exactly 160 KiB -> max waves/CU with (512,8).
// LDS (dsd): sXs[32x72] sXm[32x72] sW21b[64x72] sW22b[64x72] sS1[32x64 f]
//            = 35840 B.
__global__ __launch_bounds__(512, 8) void k_main(
    const float* __restrict__ E_s, const unsigned short* __restrict__ Ebf,
    const float* __restrict__ E_d,
    const float* __restrict__ W21, const float* __restrict__ W22,
    const float* __restrict__ W11, const float* __restrict__ W12,
    const float* __restrict__ W3, const float* __restrict__ W21u,
    const float* __restrict__ W22u, const float* __restrict__ W1u,
    const int* __restrict__ label, const int* __restrict__ dsd_1,
    const int* __restrict__ dsd_2, const int* __restrict__ usu_1,
    const int* __restrict__ usu_2, const int* __restrict__ usu_3,
    float* __restrict__ emb_dise, float* __restrict__ emb_user)
{
    __shared__ float4 smraw[2560];   // 40960 B
    const int tid = threadIdx.x, lane = tid & 63, w = rfl(tid >> 6);
    const int m_ = lane & 15, quad = lane >> 4;

    if (blockIdx.x < 1024) {
        // ================= usu branch: one block per b, 8 waves =========
        const int b = blockIdx.x;
        unsigned short* sXb   = (unsigned short*)smraw;   // 64x72
        unsigned short* sW3b  = sXb + 4608;
        unsigned short* sW21b = sW3b + 4608;
        unsigned short* sW22b = sW21b + 4608;
        float* sA2  = (float*)(sW22b + 4608);             // 8x64
        float* sES1 = sA2 + 512;                          // 8x64
        unsigned short* sXs = sXb;                        // phase3: 16x72
        unsigned short* sXm = sXb + 16 * XP;

        const int sub = lane >> 4, cg = lane & 15;

        // Hoist indices: one coalesced load per row.
        int idv[8];
#pragma unroll
        for (int i = 0; i < 8; ++i)
            idv[i] = usu_3[((size_t)(b * 64 + w * 8 + i)) * 16 + cg];

        // Phase 0: W3/W21u/W22u -> bf16 LDS (8 elems/thread each).
        {
            int row = tid >> 3, c0 = (tid & 7) << 3;
            const float* p3 = W3 + row * 64 + c0;
            const float* p1 = W21u + row * 64 + c0;
            const float* p2 = W22u + row * 64 + c0;
#pragma unroll
            for (int i = 0; i < 8; ++i) {
                sW3b[row * XP + c0 + i]  = bf16bits(p3[i]);
                sW21b[row * XP + c0 + i] = bf16bits(p1[i]);
                sW22b[row * XP + c0 + i] = bf16bits(p2[i]);
            }
        }

        // Phase 1: transposed gather + masked-avg (R8-verified), R20:
        // depth-3 row pipeline — rows i+1,i+2's shfl+loads in flight while
        // row i reduces (~12 loads in flight).
        uint2 vbuf[3][4];
#pragma unroll
        for (int r = 0; r < 2; ++r) {
#pragma unroll
            for (int k = 0; k < 4; ++k) {
                int id = __shfl(idv[r], k * 4 + sub, 64);
                vbuf[r][k] =
                    *reinterpret_cast<const uint2*>(Ebf + (size_t)id * 64 + cg * 4);
            }
        }
#pragma unroll
        for (int i = 0; i < 8; ++i) {
            const int cur = i % 3;
            if (i < 6) {
                const int pre = (i + 2) % 3;
#pragma unroll
                for (int k = 0; k < 4; ++k) {
                    int id = __shfl(idv[i + 2], k * 4 + sub, 64);
                    vbuf[pre][k] =
                        *reinterpret_cast<const uint2*>(Ebf + (size_t)id * 64 + cg * 4);
                }
            }
            int ql = w * 8 + i;
            unsigned long long nzm = __ballot(idv[i] != 0) & 0xFFFFull;
            int cnt = (int)__popcll(nzm);
            float wgt = cnt > 0 ? 1.f / ((float)cnt + 1e-8f) : 0.f;
            float a0 = 0.f, a1 = 0.f, a2 = 0.f, a3 = 0.f;
#pragma unroll
            for (int k = 0; k < 4; ++k) {
                uint2 v = vbuf[cur][k];
                a0 += bflo(v.x); a1 += bfhi(v.x);
                a2 += bflo(v.y); a3 += bfhi(v.y);
            }
            a0 += __shfl_xor(a0, 16, 64); a1 += __shfl_xor(a1, 16, 64);
            a2 += __shfl_xor(a2, 16, 64); a3 += __shfl_xor(a3, 16, 64);
            a0 += __shfl_xor(a0, 32, 64); a1 += __shfl_xor(a1, 32, 64);
            a2 += __shfl_xor(a2, 32, 64); a3 += __shfl_xor(a3, 32, 64);
            a0 *= wgt; a1 *= wgt; a2 *= wgt; a3 *= wgt;
            unsigned int p0 = ((unsigned int)bf16bits(a1) << 16) | bf16bits(a0);
            unsigned int p1 = ((unsigned int)bf16bits(a3) << 16) | bf16bits(a2);
            if (sub == 0) {
                uint2 st; st.x = p0; st.y = p1;
                *reinterpret_cast<uint2*>(sXb + ql * XP + cg * 4) = st;
            }
        }
        __syncthreads();

        // Phase 2: Y = leaky(X @ W3^T) via MFMA; u2-reduction in C-layout.
        {
            const int wt = w >> 1, J0 = (w & 1) * 2;
            const int base = (16 * wt + m_) * XP + quad * 8;
            short8 a0 = *(const short8*)(sXb + base);
            short8 a1 = *(const short8*)(sXb + base + 32);
            int cp0 = 0, cp1 = 0;
            const int* m2 = usu_2 + (b * 8 + 2 * wt) * 8;
#pragma unroll
            for (int u = 0; u < 8; ++u) { cp0 += (m2[u] != 0); cp1 += (m2[u + 8] != 0); }
            float wg0 = cp0 > 0 ? 1.f / ((float)cp0 + 1e-8f) : 0.f;
            float wg1 = cp1 > 0 ? 1.f / ((float)cp1 + 1e-8f) : 0.f;
#pragma unroll
            for (int jj = 0; jj < 2; ++jj) {
                int J = J0 + jj;
                const int wb = (16 * J + m_) * XP + quad * 8;
                short8 b0 = *(const short8*)(sW3b + wb);
                short8 b1 = *(const short8*)(sW3b + wb + 32);
                f32x4 acc = {0.f, 0.f, 0.f, 0.f};
                acc = __builtin_amdgcn_mfma_f32_16x16x32_bf16(a0, b0, acc, 0, 0, 0);
                acc = __builtin_amdgcn_mfma_f32_16x16x32_bf16(a1, b1, acc, 0, 0, 0);
                float t = leakyf(acc[0]) + leakyf(acc[1]) + leakyf(acc[2]) + leakyf(acc[3]);
                t += __shfl_xor(t, 16, 64);
                if (quad == 0) sA2[(2 * wt + 0) * 64 + J * 16 + m_] = t * wg0;
                if (quad == 2) sA2[(2 * wt + 1) * 64 + J * 16 + m_] = t * wg1;
            }
        }
        __syncthreads();

        // Phase 3a: build stage-2 A rows (wave w -> p=w): xs=x+u, xm=x*u.
        {
            int p = w;
            float x = sA2[p * 64 + lane];
            float u1e = E_s[(size_t)usu_1[b * 8 + p] * 64 + lane];
            sXs[p * XP + lane] = bf16bits(x + u1e);
            sXm[p * XP + lane] = bf16bits(x * u1e);
        }
        __syncthreads();

        // Phase 3b: stage-2 MFMA (waves 0-3, J=w): rows 0-7 valid.
        if (w < 4) {
            f32x4 acc = pair_mfma(sXs, sXm, sW21b, sW22b, m_, 16 * w + m_, quad);
            if (quad < 2) {
#pragma unroll
                for (int r = 0; r < 4; ++r)
                    sES1[(quad * 4 + r) * 64 + w * 16 + m_] = leakyf(acc[r]);
            }
        }
        __syncthreads();

        // Phase 3c: W1u fp32 swizzled over sW21b/sW22b region (dead now).
        stage_w512((float*)sW21b, W1u, tid);
        __syncthreads();

        // Phase 3d: final masked-avg + W1u transform (wave 0).
        if (w == 0) {
            float sE = 0.f; int cnt = 0;
            const int* u1i = usu_1 + b * 8;
#pragma unroll
            for (int h = 0; h < 8; ++h) {
                sE += sES1[h * 64 + lane];
                cnt += (u1i[h] != 0);
            }
            float wgt = cnt > 0 ? 1.f / ((float)cnt + 1e-8f) : 0.f;
            float eu = leakyf(dot1_lds(sE * wgt, (float*)sW21b, lane));
            emb_user[(size_t)b * 64 + lane] = eu;
        }
    } else {
        // ================= dsd branch: 4 b per block, 8 waves, MFMA ======
        const int b0 = (blockIdx.x - 1024) * 4;
        unsigned short* sXs   = (unsigned short*)smraw;   // 32x72
        unsigned short* sXm   = sXs + 2304;               // 32x72
        unsigned short* sW21b = sXm + 2304;               // 64x72 (W21 -> W11)
        unsigned short* sW22b = sW21b + 4608;             // 64x72 (W22 -> W12)
        float* sS1 = (float*)(sW22b + 4608);              // 32x64 fp32

        // Phase 0: W21/W22 -> bf16 LDS.
        {
            int row = tid >> 3, c0 = (tid & 7) << 3;
            const float* p1 = W21 + row * 64 + c0;
            const float* p2 = W22 + row * 64 + c0;
#pragma unroll
            for (int i = 0; i < 8; ++i) {
                sW21b[row * XP + c0 + i] = bf16bits(p1[i]);
                sW22b[row * XP + c0 + i] = bf16bits(p2[i]);
            }
        }

        // Phase 1: gathers + build stage-1 A rows (wave w: rows 4w..4w+3).
#pragma unroll
        for (int i = 0; i < 4; ++i) {
            int rl = w * 4 + i;
            int row = b0 * 8 + rl;
            int is = dsd_1[row];
            float es = E_s[(size_t)is * 64 + lane];
            const int* d2 = dsd_2 + row * 8;
            float sA = 0.f; int cnt = 0;
#pragma unroll
            for (int h = 0; h < 8; ++h) {
                int id = d2[h];
                cnt += (id != 0);
                sA += E_d[(size_t)id * 64 + lane];   // E_d[0] == 0
            }
            float wgt = cnt > 0 ? 1.f / ((float)cnt + 1e-8f) : 0.f;
            float A = sA * wgt;
            sXs[rl * XP + lane] = bf16bits(A + es);
            sXm[rl * XP + lane] = bf16bits(A * es);
        }
        __syncthreads();

        // Phase 2: stage-1 MFMA: wave w -> Mt=w>>2, J=w&3; all 16 rows valid.
        {
            const int Mt = w >> 2, J = w & 3;
            f32x4 acc = pair_mfma(sXs, sXm, sW21b, sW22b,
                                  16 * Mt + m_, 16 * J + m_, quad);
#pragma unroll
            for (int r = 0; r < 4; ++r)
                sS1[(16 * Mt + quad * 4 + r) * 64 + J * 16 + m_] = leakyf(acc[r]);
        }
        __syncthreads();

        // Phase 3: waves 0-3 build stage-2 A rows (p=w -> b0+w);
        //          waves 4-7 convert W11/W12 over W21/W22 slots.
        if (w < 4) {
            int bb = b0 + w;
            float sE = 0.f; int cnt = 0;
            const int* d1 = dsd_1 + bb * 8;
#pragma unroll
            for (int h = 0; h < 8; ++h) {
                sE += sS1[(w * 8 + h) * 64 + lane];
                cnt += (d1[h] != 0);
            }
            float wgt = cnt > 0 ? 1.f / ((float)cnt + 1e-8f) : 0.f;
            float A3 = sE * wgt;
            float td = E_d[(size_t)label[bb] * 64 + lane];
            sXs[w * XP + lane] = bf16bits(A3 + td);
            sXm[w * XP + lane] = bf16bits(A3 * td);
        } else {
            int t2 = tid - 256;                 // 0..255
            int row = t2 >> 2, c0 = (t2 & 3) << 4;
            const float* p1 = W11 + row * 64 + c0;
            const float* p2 = W12 + row * 64 + c0;
#pragma unroll
            for (int i = 0; i < 16; ++i) {
                sW21b[row * XP + c0 + i] = bf16bits(p1[i]);
                sW22b[row * XP + c0 + i] = bf16bits(p2[i]);
            }
        }
        __syncthreads();

        // Phase 4: stage-2 MFMA (waves 0-3, J=w): rows 0-3 valid (quad 0).
        if (w < 4) {
            f32x4 acc = pair_mfma(sXs, sXm, sW21b, sW22b, m_, 16 * w + m_, quad);
            if (quad == 0) {
#pragma unroll
                for (int r = 0; r < 4; ++r)
                    emb_dise[(size_t)(b0 + r) * 64 + w * 16 + m_] = leakyf(acc[r]);
            }
        }
    }
}

// ---- epilogue: out[b] = dot(emb_dise[b], emb_user[b]) ----
__global__ __launch_bounds__(256) void k_dot(const float* __restrict__ ed,
                                             const float* __restrict__ eu,
                                             float* __restrict__ out) {
    const int lane = threadIdx.x & 63;
    const int b = rfl((int)((blockIdx.x * blockDim.x + threadIdx.x) >> 6));
    float pr = ed[(size_t)b * 64 + lane] * eu[(size_t)b * 64 + lane];
#pragma unroll
    for (int off = 32; off > 0; off >>= 1) pr += __shfl_down(pr, off, 64);
    if (lane == 0) out[b] = pr;
}

extern "C" void kernel_launch(void* const* d_in, const int* in_sizes, int n_in,
                              void* d_out, int out_size, void* d_ws, size_t ws_size,
                              hipStream_t stream) {
    const float* E_s  = (const float*)d_in[0];
    const float* E_d  = (const float*)d_in[1];
    const float* W_dsd_21 = (const float*)d_in[2];
    const float* W_dsd_22 = (const float*)d_in[3];
    const float* W_dsd_11 = (const float*)d_in[4];
    const float* W_dsd_12 = (const float*)d_in[5];
    const float* W_usu_3  = (const float*)d_in[6];
    const float* W_usu_21 = (const float*)d_in[7];
    const float* W_usu_22 = (const float*)d_in[8];
    const float* W_usu_1  = (const float*)d_in[9];
    const int* label = (const int*)d_in[10];
    const int* dsd_1 = (const int*)d_in[11];
    const int* dsd_2 = (const int*)d_in[12];
    const int* usu_1 = (const int*)d_in[13];
    const int* usu_2 = (const int*)d_in[14];
    const int* usu_3 = (const int*)d_in[15];
    float* out = (float*)d_out;

    // ws: Ebf [50001*64 bf16 = 6,400,128 B] | emb_dise [256 KB] | emb_user [256 KB]
    unsigned short* Ebf = (unsigned short*)d_ws;
    float* emb_dise = (float*)((char*)d_ws + 6400128);
    float* emb_user = emb_dise + 1024 * 64;

    k_cvt<<<1563, 256, 0, stream>>>(E_s, Ebf);
    k_main<<<1280, 512, 0, stream>>>(E_s, Ebf, E_d,
                                     W_dsd_21, W_dsd_22, W_dsd_11, W_dsd_12,
                                     W_usu_3, W_usu_21, W_usu_22, W_usu_1,
                                     label, dsd_1, dsd_2, usu_1, usu_2, usu_3,
                                     emb_dise, emb_user);
    k_dot<<<256, 256, 0, stream>>>(emb_dise, emb_user, out);
}

// Round 9
// 114.260 us; speedup vs baseline: 1.0198x; 1.0198x over previous
//
#include <hip/hip_runtime.h>
#include <hip/hip_bf16.h>

// HGNN forward, MI355X.
// R21 = R18 (best: 112.7us) + usu_3 gather table in fp8 e4m3 (OCP).
// Mechanism: bf16 table (6.4MB) doesn't fit per-XCD 4MiB L2 -> mixed
// L2/L3 hits ~450cy; fp8 table (3.2MB) is fully L2-resident per XCD ->
// ~200cy hits + halved bytes. Only the usu_3 mass gather is quantized
// (usu_1/dsd/E_d stay fp32). Predicted absmax ~1e-3 (was 1.22e-4);
// if threshold fails, R22 reverts to R18.
// History:
//  - R14 (k_dot fold, agent atomics): FAILED +43us (L2 thrash).
//  - R15 (32-load hoist + (512,4)): +3us — occupancy loss beat MLP.
//  - R16 (depth-2 pipeline, (512,6)): 114.2us.
//  - R17 (gather hoisted to own kernel): +7.5us — lost overlap.
//  - R18 ((512,8) = 4 blocks/CU, LDS-exact): 112.7us BEST.
//  - R19 (depth-3 + interleave): 115.8; R20 (depth-3 only): 116.5 —
//    depth-3 is the regressor (64-VGPR cap), interleave ~neutral.
// Structure:
//  - k_cvt: E_s -> fp8 e4m3 table (3.2MB, hw cvt_pk_fp8).
//  - k_main: 1024 usu blocks then 256 dsd blocks (dsd-last short tail).
//  - k_dot: final 64-dot.

typedef __attribute__((ext_vector_type(8))) short short8;
typedef __attribute__((ext_vector_type(4))) float f32x4;

__device__ __forceinline__ int rfl(int v) { return __builtin_amdgcn_readfirstlane(v); }
__device__ __forceinline__ float bcastf(float v, int l) {
    return __int_as_float(__builtin_amdgcn_readlane(__float_as_int(v), l));
}
__device__ __forceinline__ float leakyf(float x) { return x >= 0.f ? x : 0.2f * x; }

__device__ __forceinline__ unsigned short bf16bits(float x) {
    __hip_bfloat16 h = __float2bfloat16(x);
    return __builtin_bit_cast(unsigned short, h);
}

// Swizzled LDS fp32 weight layout (R3-verified): element [j][k] at float4
// index 16*j + (((k>>2)+j)&15). 512-thread stager: 2 float4 per thread.
__device__ __forceinline__ void stage_w512(float* dst, const float* __restrict__ W, int tid) {
#pragma unroll
    for (int c = 0; c < 2; ++c) {
        int f4 = c * 512 + tid;
        int j = f4 >> 4, g = f4 & 15;
        float4 v = reinterpret_cast<const float4*>(W)[f4];
        reinterpret_cast<float4*>(dst)[(j << 4) + ((g + j) & 15)] = v;
    }
}

__device__ __forceinline__ float dot1_lds(float x, const float* w, int lane) {
    float a0 = 0.f, a1 = 0.f, a2 = 0.f, a3 = 0.f;
#pragma unroll
    for (int g = 0; g < 16; ++g) {
        float4 c = reinterpret_cast<const float4*>(w)[(lane << 4) + ((g + lane) & 15)];
        int k = 4 * g;
        a0 = fmaf(bcastf(x, k + 0), c.x, a0);
        a1 = fmaf(bcastf(x, k + 1), c.y, a1);
        a2 = fmaf(bcastf(x, k + 2), c.z, a2);
        a3 = fmaf(bcastf(x, k + 3), c.w, a3);
    }
    return (a0 + a1) + (a2 + a3);
}

// ---- E_s fp32 -> fp8 e4m3 table (hw packed converts, RNE) ----
__global__ __launch_bounds__(256) void k_cvt(const float* __restrict__ E_s,
                                             unsigned int* __restrict__ T8) {
    int t = blockIdx.x * 256 + threadIdx.x;
    if (t >= 400008) return;   // 50001*64/8 groups of 8 elements
    const float4* p = reinterpret_cast<const float4*>(E_s) + (size_t)t * 2;
    float4 a = p[0], b = p[1];
    unsigned int lo = 0u, hi = 0u;
    lo = (unsigned int)__builtin_amdgcn_cvt_pk_fp8_f32(a.x, a.y, (int)lo, false);
    lo = (unsigned int)__builtin_amdgcn_cvt_pk_fp8_f32(a.z, a.w, (int)lo, true);
    hi = (unsigned int)__builtin_amdgcn_cvt_pk_fp8_f32(b.x, b.y, (int)hi, false);
    hi = (unsigned int)__builtin_amdgcn_cvt_pk_fp8_f32(b.z, b.w, (int)hi, true);
    uint2 o; o.x = lo; o.y = hi;
    *reinterpret_cast<uint2*>(T8 + (size_t)t * 2) = o;
}

#define XP 72   // bf16 matrix row pitch in shorts (144 B: 16B-aligned)

// 4-MFMA pair-matmul accumulate: acc += As@Wb1(K32x2) + Am@Wb2(K32x2)
__device__ __forceinline__ f32x4 pair_mfma(
    const unsigned short* sXs, const unsigned short* sXm,
    const unsigned short* sWb1, const unsigned short* sWb2,
    int arow, int brow, int quad)
{
    const int ab = arow * XP + quad * 8;
    const int bb = brow * XP + quad * 8;
    short8 as0 = *(const short8*)(sXs + ab);
    short8 as1 = *(const short8*)(sXs + ab + 32);
    short8 am0 = *(const short8*)(sXm + ab);
    short8 am1 = *(const short8*)(sXm + ab + 32);
    short8 b10 = *(const short8*)(sWb1 + bb);
    short8 b11 = *(const short8*)(sWb1 + bb + 32);
    short8 b20 = *(const short8*)(sWb2 + bb);
    short8 b21 = *(const short8*)(sWb2 + bb + 32);
    f32x4 acc = {0.f, 0.f, 0.f, 0.f};
    acc = __builtin_amdgcn_mfma_f32_16x16x32_bf16(as0, b10, acc, 0, 0, 0);
    acc = __builtin_amdgcn_mfma_f32_16x16x32_bf16(as1, b11, acc, 0, 0, 0);
    acc = __builtin_amdgcn_mfma_f32_16x16x32_bf16(am0, b20, acc, 0, 0, 0);
    acc = __builtin_amdgcn_mfma_f32_16x16x32_bf16(am1, b21, acc, 0, 0, 0);
    return acc;
}

// LDS (usu): sXb[64x72] sW3b[64x72] sW21b[64x72] sW22b[64x72] (ushort)
//            sA2[512] sES1[512] (float) = 40960 B.  4 blocks/CU = 163840 B
//            = exactly 160 KiB -> max waves/CU with (512,8).
// LDS (dsd): sXs[32x72] sXm[32x72] sW21b[64x72] sW22b[64x72] sS1[32x64 f]
//            = 35840 B.
__global__ __launch_bounds__(512, 8) void k_main(
    const float* __restrict__ E_s, const unsigned int* __restrict__ E8,
    const float* __restrict__ E_d,
    const float* __restrict__ W21, const float* __restrict__ W22,
    const float* __restrict__ W11, const float* __restrict__ W12,
    const float* __restrict__ W3, const float* __restrict__ W21u,
    const float* __restrict__ W22u, const float* __restrict__ W1u,
    const int* __restrict__ label, const int* __restrict__ dsd_1,
    const int* __restrict__ dsd_2, const int* __restrict__ usu_1,
    const int* __restrict__ usu_2, const int* __restrict__ usu_3,
    float* __restrict__ emb_dise, float* __restrict__ emb_user)
{
    __shared__ float4 smraw[2560];   // 40960 B
    const int tid = threadIdx.x, lane = tid & 63, w = rfl(tid >> 6);
    const int m_ = lane & 15, quad = lane >> 4;

    if (blockIdx.x < 1024) {
        // ================= usu branch: one block per b, 8 waves =========
        const int b = blockIdx.x;
        unsigned short* sXb   = (unsigned short*)smraw;   // 64x72
        unsigned short* sW3b  = sXb + 4608;
        unsigned short* sW21b = sW3b + 4608;
        unsigned short* sW22b = sW21b + 4608;
        float* sA2  = (float*)(sW22b + 4608);             // 8x64
        float* sES1 = sA2 + 512;                          // 8x64
        unsigned short* sXs = sXb;                        // phase3: 16x72
        unsigned short* sXm = sXb + 16 * XP;

        const int sub = lane >> 4, cg = lane & 15;

        // Hoist indices: one coalesced load per row.
        int idv[8];
#pragma unroll
        for (int i = 0; i < 8; ++i)
            idv[i] = usu_3[((size_t)(b * 64 + w * 8 + i)) * 16 + cg];

        // Phase 0: W3/W21u/W22u -> bf16 LDS (8 elems/thread each).
        {
            int row = tid >> 3, c0 = (tid & 7) << 3;
            const float* p3 = W3 + row * 64 + c0;
            const float* p1 = W21u + row * 64 + c0;
            const float* p2 = W22u + row * 64 + c0;
#pragma unroll
            for (int i = 0; i < 8; ++i) {
                sW3b[row * XP + c0 + i]  = bf16bits(p3[i]);
                sW21b[row * XP + c0 + i] = bf16bits(p1[i]);
                sW22b[row * XP + c0 + i] = bf16bits(p2[i]);
            }
        }

        // Phase 1: transposed gather + masked-avg, depth-2 pipeline (R16),
        // R21: fp8 table — lane cg loads 4B (elements 4cg..4cg+3), decoded
        // by hw cvt_f32_fp8. Table is 3.2MB = per-XCD-L2-resident.
        unsigned int vbuf[2][4];
#pragma unroll
        for (int k = 0; k < 4; ++k) {
            int id = __shfl(idv[0], k * 4 + sub, 64);
            vbuf[0][k] = E8[(size_t)id * 16 + cg];
        }
#pragma unroll
        for (int i = 0; i < 8; ++i) {
            const int cur = i & 1, nxt = cur ^ 1;
            if (i < 7) {
#pragma unroll
                for (int k = 0; k < 4; ++k) {
                    int id = __shfl(idv[i + 1], k * 4 + sub, 64);
                    vbuf[nxt][k] = E8[(size_t)id * 16 + cg];
                }
            }
            int ql = w * 8 + i;
            unsigned long long nzm = __ballot(idv[i] != 0) & 0xFFFFull;
            int cnt = (int)__popcll(nzm);
            float wgt = cnt > 0 ? 1.f / ((float)cnt + 1e-8f) : 0.f;
            float a0 = 0.f, a1 = 0.f, a2 = 0.f, a3 = 0.f;
#pragma unroll
            for (int k = 0; k < 4; ++k) {
                unsigned int v = vbuf[cur][k];
                a0 += __builtin_amdgcn_cvt_f32_fp8(v, 0);
                a1 += __builtin_amdgcn_cvt_f32_fp8(v, 1);
                a2 += __builtin_amdgcn_cvt_f32_fp8(v, 2);
                a3 += __builtin_amdgcn_cvt_f32_fp8(v, 3);
            }
            a0 += __shfl_xor(a0, 16, 64); a1 += __shfl_xor(a1, 16, 64);
            a2 += __shfl_xor(a2, 16, 64); a3 += __shfl_xor(a3, 16, 64);
            a0 += __shfl_xor(a0, 32, 64); a1 += __shfl_xor(a1, 32, 64);
            a2 += __shfl_xor(a2, 32, 64); a3 += __shfl_xor(a3, 32, 64);
            a0 *= wgt; a1 *= wgt; a2 *= wgt; a3 *= wgt;
            unsigned int p0 = ((unsigned int)bf16bits(a1) << 16) | bf16bits(a0);
            unsigned int p1 = ((unsigned int)bf16bits(a3) << 16) | bf16bits(a2);
            if (sub == 0) {
                uint2 st; st.x = p0; st.y = p1;
                *reinterpret_cast<uint2*>(sXb + ql * XP + cg * 4) = st;
            }
        }
        __syncthreads();

        // Phase 2: Y = leaky(X @ W3^T) via MFMA; u2-reduction in C-layout.
        {
            const int wt = w >> 1, J0 = (w & 1) * 2;
            const int base = (16 * wt + m_) * XP + quad * 8;
            short8 a0 = *(const short8*)(sXb + base);
            short8 a1 = *(const short8*)(sXb + base + 32);
            int cp0 = 0, cp1 = 0;
            const int* m2 = usu_2 + (b * 8 + 2 * wt) * 8;
#pragma unroll
            for (int u = 0; u < 8; ++u) { cp0 += (m2[u] != 0); cp1 += (m2[u + 8] != 0); }
            float wg0 = cp0 > 0 ? 1.f / ((float)cp0 + 1e-8f) : 0.f;
            float wg1 = cp1 > 0 ? 1.f / ((float)cp1 + 1e-8f) : 0.f;
#pragma unroll
            for (int jj = 0; jj < 2; ++jj) {
                int J = J0 + jj;
                const int wb = (16 * J + m_) * XP + quad * 8;
                short8 b0 = *(const short8*)(sW3b + wb);
                short8 b1 = *(const short8*)(sW3b + wb + 32);
                f32x4 acc = {0.f, 0.f, 0.f, 0.f};
                acc = __builtin_amdgcn_mfma_f32_16x16x32_bf16(a0, b0, acc, 0, 0, 0);
                acc = __builtin_amdgcn_mfma_f32_16x16x32_bf16(a1, b1, acc, 0, 0, 0);
                float t = leakyf(acc[0]) + leakyf(acc[1]) + leakyf(acc[2]) + leakyf(acc[3]);
                t += __shfl_xor(t, 16, 64);
                if (quad == 0) sA2[(2 * wt + 0) * 64 + J * 16 + m_] = t * wg0;
                if (quad == 2) sA2[(2 * wt + 1) * 64 + J * 16 + m_] = t * wg1;
            }
        }
        __syncthreads();

        // Phase 3a: build stage-2 A rows (wave w -> p=w): xs=x+u, xm=x*u.
        {
            int p = w;
            float x = sA2[p * 64 + lane];
            float u1e = E_s[(size_t)usu_1[b * 8 + p] * 64 + lane];
            sXs[p * XP + lane] = bf16bits(x + u1e);
            sXm[p * XP + lane] = bf16bits(x * u1e);
        }
        __syncthreads();

        // Phase 3b: stage-2 MFMA (waves 0-3, J=w): rows 0-7 valid.
        if (w < 4) {
            f32x4 acc = pair_mfma(sXs, sXm, sW21b, sW22b, m_, 16 * w + m_, quad);
            if (quad < 2) {
#pragma unroll
                for (int r = 0; r < 4; ++r)
                    sES1[(quad * 4 + r) * 64 + w * 16 + m_] = leakyf(acc[r]);
            }
        }
        __syncthreads();

        // Phase 3c: W1u fp32 swizzled over sW21b/sW22b region (dead now).
        stage_w512((float*)sW21b, W1u, tid);
        __syncthreads();

        // Phase 3d: final masked-avg + W1u transform (wave 0).
        if (w == 0) {
            float sE = 0.f; int cnt = 0;
            const int* u1i = usu_1 + b * 8;
#pragma unroll
            for (int h = 0; h < 8; ++h) {
                sE += sES1[h * 64 + lane];
                cnt += (u1i[h] != 0);
            }
            float wgt = cnt > 0 ? 1.f / ((float)cnt + 1e-8f) : 0.f;
            float eu = leakyf(dot1_lds(sE * wgt, (float*)sW21b, lane));
            emb_user[(size_t)b * 64 + lane] = eu;
        }
    } else {
        // ================= dsd branch: 4 b per block, 8 waves, MFMA ======
        const int b0 = (blockIdx.x - 1024) * 4;
        unsigned short* sXs   = (unsigned short*)smraw;   // 32x72
        unsigned short* sXm   = sXs + 2304;               // 32x72
        unsigned short* sW21b = sXm + 2304;               // 64x72 (W21 -> W11)
        unsigned short* sW22b = sW21b + 4608;             // 64x72 (W22 -> W12)
        float* sS1 = (float*)(sW22b + 4608);              // 32x64 fp32

        // Phase 0: W21/W22 -> bf16 LDS.
        {
            int row = tid >> 3, c0 = (tid & 7) << 3;
            const float* p1 = W21 + row * 64 + c0;
            const float* p2 = W22 + row * 64 + c0;
#pragma unroll
            for (int i = 0; i < 8; ++i) {
                sW21b[row * XP + c0 + i] = bf16bits(p1[i]);
                sW22b[row * XP + c0 + i] = bf16bits(p2[i]);
            }
        }

        // Phase 1: gathers + build stage-1 A rows (wave w: rows 4w..4w+3).
#pragma unroll
        for (int i = 0; i < 4; ++i) {
            int rl = w * 4 + i;
            int row = b0 * 8 + rl;
            int is = dsd_1[row];
            float es = E_s[(size_t)is * 64 + lane];
            const int* d2 = dsd_2 + row * 8;
            float sA = 0.f; int cnt = 0;
#pragma unroll
            for (int h = 0; h < 8; ++h) {
                int id = d2[h];
                cnt += (id != 0);
                sA += E_d[(size_t)id * 64 + lane];   // E_d[0] == 0
            }
            float wgt = cnt > 0 ? 1.f / ((float)cnt + 1e-8f) : 0.f;
            float A = sA * wgt;
            sXs[rl * XP + lane] = bf16bits(A + es);
            sXm[rl * XP + lane] = bf16bits(A * es);
        }
        __syncthreads();

        // Phase 2: stage-1 MFMA: wave w -> Mt=w>>2, J=w&3; all 16 rows valid.
        {
            const int Mt = w >> 2, J = w & 3;
            f32x4 acc = pair_mfma(sXs, sXm, sW21b, sW22b,
                                  16 * Mt + m_, 16 * J + m_, quad);
#pragma unroll
            for (int r = 0; r < 4; ++r)
                sS1[(16 * Mt + quad * 4 + r) * 64 + J * 16 + m_] = leakyf(acc[r]);
        }
        __syncthreads();

        // Phase 3: waves 0-3 build stage-2 A rows (p=w -> b0+w);
        //          waves 4-7 convert W11/W12 over W21/W22 slots.
        if (w < 4) {
            int bb = b0 + w;
            float sE = 0.f; int cnt = 0;
            const int* d1 = dsd_1 + bb * 8;
#pragma unroll
            for (int h = 0; h < 8; ++h) {
                sE += sS1[(w * 8 + h) * 64 + lane];
                cnt += (d1[h] != 0);
            }
            float wgt = cnt > 0 ? 1.f / ((float)cnt + 1e-8f) : 0.f;
            float A3 = sE * wgt;
            float td = E_d[(size_t)label[bb] * 64 + lane];
            sXs[w * XP + lane] = bf16bits(A3 + td);
            sXm[w * XP + lane] = bf16bits(A3 * td);
        } else {
            int t2 = tid - 256;                 // 0..255
            int row = t2 >> 2, c0 = (t2 & 3) << 4;
            const float* p1 = W11 + row * 64 + c0;
            const float* p2 = W12 + row * 64 + c0;
#pragma unroll
            for (int i = 0; i < 16; ++i) {
                sW21b[row * XP + c0 + i] = bf16bits(p1[i]);
                sW22b[row * XP + c0 + i] = bf16bits(p2[i]);
            }
        }
        __syncthreads();

        // Phase 4: stage-2 MFMA (waves 0-3, J=w): rows 0-3 valid (quad 0).
        if (w < 4) {
            f32x4 acc = pair_mfma(sXs, sXm, sW21b, sW22b, m_, 16 * w + m_, quad);
            if (quad == 0) {
#pragma unroll
                for (int r = 0; r < 4; ++r)
                    emb_dise[(size_t)(b0 + r) * 64 + w * 16 + m_] = leakyf(acc[r]);
            }
        }
    }
}

// ---- epilogue: out[b] = dot(emb_dise[b], emb_user[b]) ----
__global__ __launch_bounds__(256) void k_dot(const float* __restrict__ ed,
                                             const float* __restrict__ eu,
                                             float* __restrict__ out) {
    const int lane = threadIdx.x & 63;
    const int b = rfl((int)((blockIdx.x * blockDim.x + threadIdx.x) >> 6));
    float pr = ed[(size_t)b * 64 + lane] * eu[(size_t)b * 64 + lane];
#pragma unroll
    for (int off = 32; off > 0; off >>= 1) pr += __shfl_down(pr, off, 64);
    if (lane == 0) out[b] = pr;
}

extern "C" void kernel_launch(void* const* d_in, const int* in_sizes, int n_in,
                              void* d_out, int out_size, void* d_ws, size_t ws_size,
                              hipStream_t stream) {
    const float* E_s  = (const float*)d_in[0];
    const float* E_d  = (const float*)d_in[1];
    const float* W_dsd_21 = (const float*)d_in[2];
    const float* W_dsd_22 = (const float*)d_in[3];
    const float* W_dsd_11 = (const float*)d_in[4];
    const float* W_dsd_12 = (const float*)d_in[5];
    const float* W_usu_3  = (const float*)d_in[6];
    const float* W_usu_21 = (const float*)d_in[7];
    const float* W_usu_22 = (const float*)d_in[8];
    const float* W_usu_1  = (const float*)d_in[9];
    const int* label = (const int*)d_in[10];
    const int* dsd_1 = (const int*)d_in[11];
    const int* dsd_2 = (const int*)d_in[12];
    const int* usu_1 = (const int*)d_in[13];
    const int* usu_2 = (const int*)d_in[14];
    const int* usu_3 = (const int*)d_in[15];
    float* out = (float*)d_out;

    // ws: E8 fp8 table [50001*64 = 3,200,064 B -> pad 3,200,128] |
    //     emb_dise [256 KB] | emb_user [256 KB]
    unsigned int* E8 = (unsigned int*)d_ws;
    float* emb_dise = (float*)((char*)d_ws + 3200128);
    float* emb_user = emb_dise + 1024 * 64;

    k_cvt<<<1563, 256, 0, stream>>>(E_s, E8);
    k_main<<<1280, 512, 0, stream>>>(E_s, E8, E_d,
                                     W_dsd_21, W_dsd_22, W_dsd_11, W_dsd_12,
                                     W_usu_3, W_usu_21, W_usu_22, W_usu_1,
                                     label, dsd_1, dsd_2, usu_1, usu_2, usu_3,
                                     emb_dise, emb_user);
    k_dot<<<256, 256, 0, stream>>>(emb_dise, emb_user, out);
}

// Round 10
// 112.189 us; speedup vs baseline: 1.0387x; 1.0185x over previous
//
#include <hip/hip_runtime.h>
#include <hip/hip_bf16.h>

// HGNN forward, MI355X.
// R22 = R18 (best: 112.7us) + single code-motion: usu phase-0 weight
// staging moved BETWEEN the gather prologue and the gather main loop, so
// row-0's scattered loads (longest latency in kernel) issue first and the
// ~60 VALU ops of weight staging hide under them. Zero resource change.
// History:
//  - R14 (k_dot fold, agent atomics): FAILED +43us (L2 thrash).
//  - R15 (32-load hoist + (512,4)): +3us — occupancy loss beat MLP.
//  - R16 (depth-2 pipeline, (512,6)): 114.2us.
//  - R17 (gather hoisted to own kernel): +7.5us — lost overlap.
//  - R18 ((512,8) = 4 blocks/CU, LDS-exact): 112.7us BEST.
//  - R19/R20: depth-3 regresses (+3-4us) with or without interleave.
//  - R21 (fp8 e4m3 L2-resident table): 114.3 — NEUTRAL; gather is not
//    load-latency-bound at 32 waves/CU; issue order is what's left.
// Structure:
//  - k_cvt: E_s -> bf16 table (6.4MB; halves gather lines, R5).
//  - k_main: 1024 usu blocks then 256 dsd blocks (dsd-last short tail).
//  - k_dot: final 64-dot.

typedef __attribute__((ext_vector_type(8))) short short8;
typedef __attribute__((ext_vector_type(8))) unsigned short ushort8;
typedef __attribute__((ext_vector_type(4))) float f32x4;

__device__ __forceinline__ int rfl(int v) { return __builtin_amdgcn_readfirstlane(v); }
__device__ __forceinline__ float bcastf(float v, int l) {
    return __int_as_float(__builtin_amdgcn_readlane(__float_as_int(v), l));
}
__device__ __forceinline__ float leakyf(float x) { return x >= 0.f ? x : 0.2f * x; }

__device__ __forceinline__ unsigned short bf16bits(float x) {
    __hip_bfloat16 h = __float2bfloat16(x);
    return __builtin_bit_cast(unsigned short, h);
}
__device__ __forceinline__ float bflo(unsigned int u) { return __uint_as_float(u << 16); }
__device__ __forceinline__ float bfhi(unsigned int u) { return __uint_as_float(u & 0xffff0000u); }

// Swizzled LDS fp32 weight layout (R3-verified): element [j][k] at float4
// index 16*j + (((k>>2)+j)&15). 512-thread stager: 2 float4 per thread.
__device__ __forceinline__ void stage_w512(float* dst, const float* __restrict__ W, int tid) {
#pragma unroll
    for (int c = 0; c < 2; ++c) {
        int f4 = c * 512 + tid;
        int j = f4 >> 4, g = f4 & 15;
        float4 v = reinterpret_cast<const float4*>(W)[f4];
        reinterpret_cast<float4*>(dst)[(j << 4) + ((g + j) & 15)] = v;
    }
}

__device__ __forceinline__ float dot1_lds(float x, const float* w, int lane) {
    float a0 = 0.f, a1 = 0.f, a2 = 0.f, a3 = 0.f;
#pragma unroll
    for (int g = 0; g < 16; ++g) {
        float4 c = reinterpret_cast<const float4*>(w)[(lane << 4) + ((g + lane) & 15)];
        int k = 4 * g;
        a0 = fmaf(bcastf(x, k + 0), c.x, a0);
        a1 = fmaf(bcastf(x, k + 1), c.y, a1);
        a2 = fmaf(bcastf(x, k + 2), c.z, a2);
        a3 = fmaf(bcastf(x, k + 3), c.w, a3);
    }
    return (a0 + a1) + (a2 + a3);
}

// ---- E_s fp32 -> bf16 table ----
__global__ __launch_bounds__(256) void k_cvt(const float* __restrict__ E_s,
                                             unsigned short* __restrict__ T) {
    int t = blockIdx.x * 256 + threadIdx.x;
    if (t >= 400008) return;
    const float4* p = reinterpret_cast<const float4*>(E_s) + (size_t)t * 2;
    float4 a = p[0], b = p[1];
    ushort8 o;
    o[0] = bf16bits(a.x); o[1] = bf16bits(a.y); o[2] = bf16bits(a.z); o[3] = bf16bits(a.w);
    o[4] = bf16bits(b.x); o[5] = bf16bits(b.y); o[6] = bf16bits(b.z); o[7] = bf16bits(b.w);
    *(reinterpret_cast<ushort8*>(T) + t) = o;
}

#define XP 72   // bf16 matrix row pitch in shorts (144 B: 16B-aligned)

// 4-MFMA pair-matmul accumulate: acc += As@Wb1(K32x2) + Am@Wb2(K32x2)
__device__ __forceinline__ f32x4 pair_mfma(
    const unsigned short* sXs, const unsigned short* sXm,
    const unsigned short* sWb1, const unsigned short* sWb2,
    int arow, int brow, int quad)
{
    const int ab = arow * XP + quad * 8;
    const int bb = brow * XP + quad * 8;
    short8 as0 = *(const short8*)(sXs + ab);
    short8 as1 = *(const short8*)(sXs + ab + 32);
    short8 am0 = *(const short8*)(sXm + ab);
    short8 am1 = *(const short8*)(sXm + ab + 32);
    short8 b10 = *(const short8*)(sWb1 + bb);
    short8 b11 = *(const short8*)(sWb1 + bb + 32);
    short8 b20 = *(const short8*)(sWb2 + bb);
    short8 b21 = *(const short8*)(sWb2 + bb + 32);
    f32x4 acc = {0.f, 0.f, 0.f, 0.f};
    acc = __builtin_amdgcn_mfma_f32_16x16x32_bf16(as0, b10, acc, 0, 0, 0);
    acc = __builtin_amdgcn_mfma_f32_16x16x32_bf16(as1, b11, acc, 0, 0, 0);
    acc = __builtin_amdgcn_mfma_f32_16x16x32_bf16(am0, b20, acc, 0, 0, 0);
    acc = __builtin_amdgcn_mfma_f32_16x16x32_bf16(am1, b21, acc, 0, 0, 0);
    return acc;
}

// LDS (usu): sXb[64x72] sW3b[64x72] sW21b[64x72] sW22b[64x72] (ushort)
//            sA2[512] sES1[512] (float) = 40960 B.  4 blocks/CU = 163840 B
//            = exactly 160 KiB -> max waves/CU with (512,8).
// LDS (dsd): sXs[32x72] sXm[32x72] sW21b[64x72] sW22b[64x72] sS1[32x64 f]
//            = 35840 B.
__global__ __launch_bounds__(512, 8) void k_main(
    const float* __restrict__ E_s, const unsigned short* __restrict__ Ebf,
    const float* __restrict__ E_d,
    const float* __restrict__ W21, const float* __restrict__ W22,
    const float* __restrict__ W11, const float* __restrict__ W12,
    const float* __restrict__ W3, const float* __restrict__ W21u,
    const float* __restrict__ W22u, const float* __restrict__ W1u,
    const int* __restrict__ label, const int* __restrict__ dsd_1,
    const int* __restrict__ dsd_2, const int* __restrict__ usu_1,
    const int* __restrict__ usu_2, const int* __restrict__ usu_3,
    float* __restrict__ emb_dise, float* __restrict__ emb_user)
{
    __shared__ float4 smraw[2560];   // 40960 B
    const int tid = threadIdx.x, lane = tid & 63, w = rfl(tid >> 6);
    const int m_ = lane & 15, quad = lane >> 4;

    if (blockIdx.x < 1024) {
        // ================= usu branch: one block per b, 8 waves =========
        const int b = blockIdx.x;
        unsigned short* sXb   = (unsigned short*)smraw;   // 64x72
        unsigned short* sW3b  = sXb + 4608;
        unsigned short* sW21b = sW3b + 4608;
        unsigned short* sW22b = sW21b + 4608;
        float* sA2  = (float*)(sW22b + 4608);             // 8x64
        float* sES1 = sA2 + 512;                          // 8x64
        unsigned short* sXs = sXb;                        // phase3: 16x72
        unsigned short* sXm = sXb + 16 * XP;

        const int sub = lane >> 4, cg = lane & 15;

        // Hoist indices: one coalesced load per row.
        int idv[8];
#pragma unroll
        for (int i = 0; i < 8; ++i)
            idv[i] = usu_3[((size_t)(b * 64 + w * 8 + i)) * 16 + cg];

        // Phase 1 prologue (R22: issue FIRST): row 0's scattered loads fly
        // before the VALU-heavy weight staging, which then hides under them.
        uint2 vbuf[2][4];
#pragma unroll
        for (int k = 0; k < 4; ++k) {
            int id = __shfl(idv[0], k * 4 + sub, 64);
            vbuf[0][k] = *reinterpret_cast<const uint2*>(Ebf + (size_t)id * 64 + cg * 4);
        }

        // Phase 0: W3/W21u/W22u -> bf16 LDS (8 elems/thread each);
        // executes under row-0 gather latency.
        {
            int row = tid >> 3, c0 = (tid & 7) << 3;
            const float* p3 = W3 + row * 64 + c0;
            const float* p1 = W21u + row * 64 + c0;
            const float* p2 = W22u + row * 64 + c0;
#pragma unroll
            for (int i = 0; i < 8; ++i) {
                sW3b[row * XP + c0 + i]  = bf16bits(p3[i]);
                sW21b[row * XP + c0 + i] = bf16bits(p1[i]);
                sW22b[row * XP + c0 + i] = bf16bits(p2[i]);
            }
        }

        // Phase 1 main loop: transposed gather + masked-avg (R8-verified),
        // depth-2 row pipeline (R16).
#pragma unroll
        for (int i = 0; i < 8; ++i) {
            const int cur = i & 1, nxt = cur ^ 1;
            if (i < 7) {
#pragma unroll
                for (int k = 0; k < 4; ++k) {
                    int id = __shfl(idv[i + 1], k * 4 + sub, 64);
                    vbuf[nxt][k] =
                        *reinterpret_cast<const uint2*>(Ebf + (size_t)id * 64 + cg * 4);
                }
            }
            int ql = w * 8 + i;
            unsigned long long nzm = __ballot(idv[i] != 0) & 0xFFFFull;
            int cnt = (int)__popcll(nzm);
            float wgt = cnt > 0 ? 1.f / ((float)cnt + 1e-8f) : 0.f;
            float a0 = 0.f, a1 = 0.f, a2 = 0.f, a3 = 0.f;
#pragma unroll
            for (int k = 0; k < 4; ++k) {
                uint2 v = vbuf[cur][k];
                a0 += bflo(v.x); a1 += bfhi(v.x);
                a2 += bflo(v.y); a3 += bfhi(v.y);
            }
            a0 += __shfl_xor(a0, 16, 64); a1 += __shfl_xor(a1, 16, 64);
            a2 += __shfl_xor(a2, 16, 64); a3 += __shfl_xor(a3, 16, 64);
            a0 += __shfl_xor(a0, 32, 64); a1 += __shfl_xor(a1, 32, 64);
            a2 += __shfl_xor(a2, 32, 64); a3 += __shfl_xor(a3, 32, 64);
            a0 *= wgt; a1 *= wgt; a2 *= wgt; a3 *= wgt;
            unsigned int p0 = ((unsigned int)bf16bits(a1) << 16) | bf16bits(a0);
            unsigned int p1 = ((unsigned int)bf16bits(a3) << 16) | bf16bits(a2);
            if (sub == 0) {
                uint2 st; st.x = p0; st.y = p1;
                *reinterpret_cast<uint2*>(sXb + ql * XP + cg * 4) = st;
            }
        }
        __syncthreads();

        // Phase 2: Y = leaky(X @ W3^T) via MFMA; u2-reduction in C-layout.
        {
            const int wt = w >> 1, J0 = (w & 1) * 2;
            const int base = (16 * wt + m_) * XP + quad * 8;
            short8 a0 = *(const short8*)(sXb + base);
            short8 a1 = *(const short8*)(sXb + base + 32);
            int cp0 = 0, cp1 = 0;
            const int* m2 = usu_2 + (b * 8 + 2 * wt) * 8;
#pragma unroll
            for (int u = 0; u < 8; ++u) { cp0 += (m2[u] != 0); cp1 += (m2[u + 8] != 0); }
            float wg0 = cp0 > 0 ? 1.f / ((float)cp0 + 1e-8f) : 0.f;
            float wg1 = cp1 > 0 ? 1.f / ((float)cp1 + 1e-8f) : 0.f;
#pragma unroll
            for (int jj = 0; jj < 2; ++jj) {
                int J = J0 + jj;
                const int wb = (16 * J + m_) * XP + quad * 8;
                short8 b0 = *(const short8*)(sW3b + wb);
                short8 b1 = *(const short8*)(sW3b + wb + 32);
                f32x4 acc = {0.f, 0.f, 0.f, 0.f};
                acc = __builtin_amdgcn_mfma_f32_16x16x32_bf16(a0, b0, acc, 0, 0, 0);
                acc = __builtin_amdgcn_mfma_f32_16x16x32_bf16(a1, b1, acc, 0, 0, 0);
                float t = leakyf(acc[0]) + leakyf(acc[1]) + leakyf(acc[2]) + leakyf(acc[3]);
                t += __shfl_xor(t, 16, 64);
                if (quad == 0) sA2[(2 * wt + 0) * 64 + J * 16 + m_] = t * wg0;
                if (quad == 2) sA2[(2 * wt + 1) * 64 + J * 16 + m_] = t * wg1;
            }
        }
        __syncthreads();

        // Phase 3a: build stage-2 A rows (wave w -> p=w): xs=x+u, xm=x*u.
        {
            int p = w;
            float x = sA2[p * 64 + lane];
            float u1e = E_s[(size_t)usu_1[b * 8 + p] * 64 + lane];
            sXs[p * XP + lane] = bf16bits(x + u1e);
            sXm[p * XP + lane] = bf16bits(x * u1e);
        }
        __syncthreads();

        // Phase 3b: stage-2 MFMA (waves 0-3, J=w): rows 0-7 valid.
        if (w < 4) {
            f32x4 acc = pair_mfma(sXs, sXm, sW21b, sW22b, m_, 16 * w + m_, quad);
            if (quad < 2) {
#pragma unroll
                for (int r = 0; r < 4; ++r)
                    sES1[(quad * 4 + r) * 64 + w * 16 + m_] = leakyf(acc[r]);
            }
        }
        __syncthreads();

        // Phase 3c: W1u fp32 swizzled over sW21b/sW22b region (dead now).
        stage_w512((float*)sW21b, W1u, tid);
        __syncthreads();

        // Phase 3d: final masked-avg + W1u transform (wave 0).
        if (w == 0) {
            float sE = 0.f; int cnt = 0;
            const int* u1i = usu_1 + b * 8;
#pragma unroll
            for (int h = 0; h < 8; ++h) {
                sE += sES1[h * 64 + lane];
                cnt += (u1i[h] != 0);
            }
            float wgt = cnt > 0 ? 1.f / ((float)cnt + 1e-8f) : 0.f;
            float eu = leakyf(dot1_lds(sE * wgt, (float*)sW21b, lane));
            emb_user[(size_t)b * 64 + lane] = eu;
        }
    } else {
        // ================= dsd branch: 4 b per block, 8 waves, MFMA ======
        const int b0 = (blockIdx.x - 1024) * 4;
        unsigned short* sXs   = (unsigned short*)smraw;   // 32x72
        unsigned short* sXm   = sXs + 2304;               // 32x72
        unsigned short* sW21b = sXm + 2304;               // 64x72 (W21 -> W11)
        unsigned short* sW22b = sW21b + 4608;             // 64x72 (W22 -> W12)
        float* sS1 = (float*)(sW22b + 4608);              // 32x64 fp32

        // Phase 0: W21/W22 -> bf16 LDS.
        {
            int row = tid >> 3, c0 = (tid & 7) << 3;
            const float* p1 = W21 + row * 64 + c0;
            const float* p2 = W22 + row * 64 + c0;
#pragma unroll
            for (int i = 0; i < 8; ++i) {
                sW21b[row * XP + c0 + i] = bf16bits(p1[i]);
                sW22b[row * XP + c0 + i] = bf16bits(p2[i]);
            }
        }

        // Phase 1: gathers + build stage-1 A rows (wave w: rows 4w..4w+3).
#pragma unroll
        for (int i = 0; i < 4; ++i) {
            int rl = w * 4 + i;
            int row = b0 * 8 + rl;
            int is = dsd_1[row];
            float es = E_s[(size_t)is * 64 + lane];
            const int* d2 = dsd_2 + row * 8;
            float sA = 0.f; int cnt = 0;
#pragma unroll
            for (int h = 0; h < 8; ++h) {
                int id = d2[h];
                cnt += (id != 0);
                sA += E_d[(size_t)id * 64 + lane];   // E_d[0] == 0
            }
            float wgt = cnt > 0 ? 1.f / ((float)cnt + 1e-8f) : 0.f;
            float A = sA * wgt;
            sXs[rl * XP + lane] = bf16bits(A + es);
            sXm[rl * XP + lane] = bf16bits(A * es);
        }
        __syncthreads();

        // Phase 2: stage-1 MFMA: wave w -> Mt=w>>2, J=w&3; all 16 rows valid.
        {
            const int Mt = w >> 2, J = w & 3;
            f32x4 acc = pair_mfma(sXs, sXm, sW21b, sW22b,
                                  16 * Mt + m_, 16 * J + m_, quad);
#pragma unroll
            for (int r = 0; r < 4; ++r)
                sS1[(16 * Mt + quad * 4 + r) * 64 + J * 16 + m_] = leakyf(acc[r]);
        }
        __syncthreads();

        // Phase 3: waves 0-3 build stage-2 A rows (p=w -> b0+w);
        //          waves 4-7 convert W11/W12 over W21/W22 slots.
        if (w < 4) {
            int bb = b0 + w;
            float sE = 0.f; int cnt = 0;
            const int* d1 = dsd_1 + bb * 8;
#pragma unroll
            for (int h = 0; h < 8; ++h) {
                sE += sS1[(w * 8 + h) * 64 + lane];
                cnt += (d1[h] != 0);
            }
            float wgt = cnt > 0 ? 1.f / ((float)cnt + 1e-8f) : 0.f;
            float A3 = sE * wgt;
            float td = E_d[(size_t)label[bb] * 64 + lane];
            sXs[w * XP + lane] = bf16bits(A3 + td);
            sXm[w * XP + lane] = bf16bits(A3 * td);
        } else {
            int t2 = tid - 256;                 // 0..255
            int row = t2 >> 2, c0 = (t2 & 3) << 4;
            const float* p1 = W11 + row * 64 + c0;
            const float* p2 = W12 + row * 64 + c0;
#pragma unroll
            for (int i = 0; i < 16; ++i) {
                sW21b[row * XP + c0 + i] = bf16bits(p1[i]);
                sW22b[row * XP + c0 + i] = bf16bits(p2[i]);
            }
        }
        __syncthreads();

        // Phase 4: stage-2 MFMA (waves 0-3, J=w): rows 0-3 valid (quad 0).
        if (w < 4) {
            f32x4 acc = pair_mfma(sXs, sXm, sW21b, sW22b, m_, 16 * w + m_, quad);
            if (quad == 0) {
#pragma unroll
                for (int r = 0; r < 4; ++r)
                    emb_dise[(size_t)(b0 + r) * 64 + w * 16 + m_] = leakyf(acc[r]);
            }
        }
    }
}

// ---- epilogue: out[b] = dot(emb_dise[b], emb_user[b]) ----
__global__ __launch_bounds__(256) void k_dot(const float* __restrict__ ed,
                                             const float* __restrict__ eu,
                                             float* __restrict__ out) {
    const int lane = threadIdx.x & 63;
    const int b = rfl((int)((blockIdx.x * blockDim.x + threadIdx.x) >> 6));
    float pr = ed[(size_t)b * 64 + lane] * eu[(size_t)b * 64 + lane];
#pragma unroll
    for (int off = 32; off > 0; off >>= 1) pr += __shfl_down(pr, off, 64);
    if (lane == 0) out[b] = pr;
}

extern "C" void kernel_launch(void* const* d_in, const int* in_sizes, int n_in,
                              void* d_out, int out_size, void* d_ws, size_t ws_size,
                              hipStream_t stream) {
    const float* E_s  = (const float*)d_in[0];
    const float* E_d  = (const float*)d_in[1];
    const float* W_dsd_21 = (const float*)d_in[2];
    const float* W_dsd_22 = (const float*)d_in[3];
    const float* W_dsd_11 = (const float*)d_in[4];
    const float* W_dsd_12 = (const float*)d_in[5];
    const float* W_usu_3  = (const float*)d_in[6];
    const float* W_usu_21 = (const float*)d_in[7];
    const float* W_usu_22 = (const float*)d_in[8];
    const float* W_usu_1  = (const float*)d_in[9];
    const int* label = (const int*)d_in[10];
    const int* dsd_1 = (const int*)d_in[11];
    const int* dsd_2 = (const int*)d_in[12];
    const int* usu_1 = (const int*)d_in[13];
    const int* usu_2 = (const int*)d_in[14];
    const int* usu_3 = (const int*)d_in[15];
    float* out = (float*)d_out;

    // ws: Ebf [50001*64 bf16 = 6,400,128 B] | emb_dise [256 KB] | emb_user [256 KB]
    unsigned short* Ebf = (unsigned short*)d_ws;
    float* emb_dise = (float*)((char*)d_ws + 6400128);
    float* emb_user = emb_dise + 1024 * 64;

    k_cvt<<<1563, 256, 0, stream>>>(E_s, Ebf);
    k_main<<<1280, 512, 0, stream>>>(E_s, Ebf, E_d,
                                     W_dsd_21, W_dsd_22, W_dsd_11, W_dsd_12,
                                     W_usu_3, W_usu_21, W_usu_22, W_usu_1,
                                     label, dsd_1, dsd_2, usu_1, usu_2, usu_3,
                                     emb_dise, emb_user);
    k_dot<<<256, 256, 0, stream>>>(emb_dise, emb_user, out);
}